// Round 2
// baseline (830.028 us; speedup 1.0000x reference)
//
#include <hip/hip_runtime.h>

#define NNODES 500000
#define KDIM 100
#define KP1 128
#define HDIM 256
#define MBLK 64
#define THREADS 256

typedef __attribute__((ext_vector_type(8))) short bf16x8;
typedef __attribute__((ext_vector_type(4))) float f32x4;

__device__ __forceinline__ unsigned rnd_bf(float f) {
    union { float f; unsigned u; } v; v.f = f;
    return v.u + 0x7fffu + ((v.u >> 16) & 1u);      // rne bias
}
// Single-instruction RNE pack of 2 f32 -> 2 bf16 (gfx950 v_cvt_pk_bf16_f32).
__device__ __forceinline__ unsigned pack2(float lo, float hi) {
    unsigned r;
    asm("v_cvt_pk_bf16_f32 %0, %1, %2" : "=v"(r) : "v"(lo), "v"(hi));
    return r;
}
// tanh(x) = 1 - 2/(1+e^{2x}); e^{2x} = 2^{x*2log2(e)}; rcp instead of IEEE div
// (default compile has no fast-math, so "/" emits div_scale/div_fmas/div_fixup).
__device__ __forceinline__ float fast_tanh(float x) {
    float e = __builtin_amdgcn_exp2f(x * 2.8853900817779268f);
    return 1.0f - 2.0f * __builtin_amdgcn_rcpf(e + 1.0f);
}
__device__ __forceinline__ float bflo(unsigned u) {
    union { unsigned u; float f; } v; v.u = u << 16; return v.f;
}
__device__ __forceinline__ float bfhi(unsigned u) {
    union { unsigned u; float f; } v; v.u = u & 0xffff0000u; return v.f;
}

// Pack weights into MFMA A-operand tiles (A = W^T): tile (kt, m16) at
// (kt*16+m16)*512; element lane*8+j = W[kt*32 + (lane>>4)*8 + j][m16*16 + (lane&15)].
__global__ void pack_all(const float* __restrict__ W1, const float* __restrict__ W2,
                         const float* __restrict__ W3,
                         unsigned short* __restrict__ w1p, unsigned short* __restrict__ w2p,
                         unsigned short* __restrict__ w3p) {
    int t = blockIdx.x * 256 + threadIdx.x;
    const float* src; unsigned short* dst; int ksrc;
    if (t < KP1 * HDIM)                    { src = W1; dst = w1p; ksrc = KDIM; }
    else if (t < KP1 * HDIM + HDIM * HDIM) { t -= KP1 * HDIM; src = W2; dst = w2p; ksrc = HDIM; }
    else                                   { t -= KP1 * HDIM + HDIM * HDIM; src = W3; dst = w3p; ksrc = HDIM; }
    int tile = t >> 9, r = t & 511, lane = r >> 3, j = r & 7;
    int kt = tile >> 4, m16 = tile & 15;
    int k = kt * 32 + ((lane >> 4) << 3) + j;
    int n = m16 * 16 + (lane & 15);
    float v = (k < ksrc) ? src[k * HDIM + n] : 0.0f;
    dst[tile * 512 + r] = (unsigned short)(rnd_bf(v) >> 16);
}

// Activations in LDS: [node][feature], element (n,f) at n*STRIDE + ((f>>3)^(n&7))*8 + (f&7).
// IN-PLACE layer: all K-loop reads of `buf` complete (barrier) before the
// epilogue overwrites `buf` with the next activations. One 32 KiB buffer
// serves 64 nodes x 256 feats for the whole layer chain.
// A = weight fragment (global, prepacked), B = activation fragment (LDS b128),
// D: row = feature (quad*4+reg -> consecutive), col = node.
template<int KSTEPS, int IN_STRIDE>
__device__ __forceinline__ void layer(unsigned short* buf,
                                      const unsigned short* __restrict__ wp,
                                      const float* __restrict__ bias, int tid) {
    const int lane = tid & 63;
    const int w = tid >> 6;            // wave owns features [w*64, w*64+64), all 64 nodes
    const int lrow = lane & 15;
    const int quad = lane >> 4;
    const int s = lrow & 7;            // swizzle key: node&7 == lrow&7 for all n-tiles

    f32x4 acc[4][4];
#pragma unroll
    for (int mt = 0; mt < 4; mt++) {
        f32x4 bv = *(const f32x4*)(bias + w * 64 + mt * 16 + quad * 4);
#pragma unroll
        for (int nt = 0; nt < 4; nt++) acc[mt][nt] = bv;
    }

    const unsigned short* wpw = wp + (w * 4) * 512 + lane * 8;

#pragma unroll 2
    for (int ks = 0; ks < KSTEPS; ks++) {
        const int gk = ks * 4 + quad;
        const int off = ((gk ^ s) << 3);
        bf16x8 b[4], a[4];
#pragma unroll
        for (int nt = 0; nt < 4; nt++)
            b[nt] = *(const bf16x8*)(buf + (nt * 16 + lrow) * IN_STRIDE + off);
#pragma unroll
        for (int mt = 0; mt < 4; mt++)
            a[mt] = *(const bf16x8*)(wpw + (ks * 16 + mt) * 512);
#pragma unroll
        for (int mt = 0; mt < 4; mt++)
#pragma unroll
            for (int nt = 0; nt < 4; nt++)
                acc[mt][nt] = __builtin_amdgcn_mfma_f32_16x16x32_bf16(a[mt], b[nt], acc[mt][nt], 0, 0, 0);
    }

    __syncthreads();                   // all waves done READING buf

#pragma unroll
    for (int mt = 0; mt < 4; mt++) {
        const int g = w * 8 + mt * 2 + (quad >> 1);      // feature granule
#pragma unroll
        for (int nt = 0; nt < 4; nt++) {
            const int node = nt * 16 + lrow;
            unsigned short* p = buf + node * HDIM + ((g ^ s) << 3) + ((quad & 1) << 2);
            f32x4 v = acc[mt][nt];
            uint2 pk;
            pk.x = pack2(fast_tanh(v[0]), fast_tanh(v[1]));
            pk.y = pack2(fast_tanh(v[2]), fast_tanh(v[3]));
            *(uint2*)p = pk;
        }
    }
    __syncthreads();                   // writes visible before next layer reads
}

__launch_bounds__(THREADS, 5)
__global__ void mlp_kernel(const float* __restrict__ ea,
                           const unsigned short* __restrict__ w1p,
                           const unsigned short* __restrict__ w2p,
                           const unsigned short* __restrict__ w3p,
                           const float* __restrict__ b1,
                           const float* __restrict__ b2,
                           const float* __restrict__ b3,
                           const float* __restrict__ w4,
                           const float* __restrict__ b4,
                           float* __restrict__ out) {
    __shared__ unsigned short X[MBLK * HDIM];       // 32 KiB, in-place all layers

    const int tid = threadIdx.x;
    const long rowbase = (long)blockIdx.x * MBLK;   // last block partial (32 rows)

    // stage e: 64 rows x 25 float4 -> bf16 (swizzled, stride KP1); zero OOB rows
    const float4* eav = (const float4*)(ea + rowbase * KDIM);
    for (int i = tid; i < MBLK * 25; i += THREADS) {
        int row = i / 25;
        int q = i - row * 25;
        float4 v = make_float4(0.f, 0.f, 0.f, 0.f);
        if (rowbase + row < NNODES) v = eav[i];
        unsigned short* p = X + row * KP1 + ((((q >> 1)) ^ (row & 7)) << 3) + ((q & 1) << 2);
        *(uint2*)p = make_uint2(pack2(v.x, v.y), pack2(v.z, v.w));
    }
    // zero-pad cols 100..127 (granule 12 upper half + granules 13..15)
    for (int i = tid; i < MBLK * 4; i += THREADS) {
        int row = i >> 2, c = i & 3;
        if (c == 0) {
            unsigned short* p = X + row * KP1 + ((12 ^ (row & 7)) << 3) + 4;
            *(uint2*)p = make_uint2(0u, 0u);
        } else {
            unsigned short* p = X + row * KP1 + (((12 + c) ^ (row & 7)) << 3);
            *(uint4*)p = make_uint4(0u, 0u, 0u, 0u);
        }
    }
    __syncthreads();

    layer<4, KP1>(X, w1p, b1, tid);     // L1: (64x128)@(128x256) tanh
    layer<8, HDIM>(X, w2p, b2, tid);    // L2
    layer<8, HDIM>(X, w3p, b3, tid);    // L3

    // head: out = sigmoid(h3 . W4 + b4); 4 lanes per node, 64 feats each
    {
        const int node = tid >> 2, part = tid & 3;
        const int s = node & 7;
        float sacc = 0.0f;
#pragma unroll
        for (int gg = 0; gg < 8; gg++) {
            const int g = part * 8 + gg;
            const uint4 hv = *(const uint4*)(X + node * HDIM + ((g ^ s) << 3));
            const float4 w0 = *(const float4*)(w4 + g * 8);
            const float4 w1 = *(const float4*)(w4 + g * 8 + 4);
            sacc += bflo(hv.x) * w0.x + bfhi(hv.x) * w0.y;
            sacc += bflo(hv.y) * w0.z + bfhi(hv.y) * w0.w;
            sacc += bflo(hv.z) * w1.x + bfhi(hv.z) * w1.y;
            sacc += bflo(hv.w) * w1.z + bfhi(hv.w) * w1.w;
        }
        sacc += __shfl_xor(sacc, 1);
        sacc += __shfl_xor(sacc, 2);
        if (part == 0 && rowbase + node < NNODES) {
            float z = sacc + b4[0];
            out[rowbase + node] =
                __builtin_amdgcn_rcpf(1.0f + __builtin_amdgcn_exp2f(-1.4426950408889634f * z));
        }
    }
}

extern "C" void kernel_launch(void* const* d_in, const int* in_sizes, int n_in,
                              void* d_out, int out_size, void* d_ws, size_t ws_size,
                              hipStream_t stream) {
    // inputs: 0:x 1:edge_index 2:edge_attr 3:W1 4:b1 5:W2 6:b2 7:W3 8:b3 9:W4 10:b4
    const float* ea = (const float*)d_in[2];
    const float* W1 = (const float*)d_in[3];
    const float* b1 = (const float*)d_in[4];
    const float* W2 = (const float*)d_in[5];
    const float* b2 = (const float*)d_in[6];
    const float* W3 = (const float*)d_in[7];
    const float* b3 = (const float*)d_in[8];
    const float* W4 = (const float*)d_in[9];
    const float* b4 = (const float*)d_in[10];
    float* out = (float*)d_out;

    unsigned short* w1p = (unsigned short*)d_ws;       // 128*256 bf16
    unsigned short* w2p = w1p + KP1 * HDIM;            // 256*256
    unsigned short* w3p = w2p + HDIM * HDIM;           // 256*256

    const int total = KP1 * HDIM + 2 * HDIM * HDIM;    // 163840
    pack_all<<<total / 256, 256, 0, stream>>>(W1, W2, W3, w1p, w2p, w3p);

    const int nblk = (NNODES + MBLK - 1) / MBLK;       // 7813, last block partial
    mlp_kernel<<<nblk, THREADS, 0, stream>>>(ea, w1p, w2p, w3p,
                                             b1, b2, b3, W4, b4, out);
}

// Round 3
// 737.560 us; speedup vs baseline: 1.1254x; 1.1254x over previous
//
#include <hip/hip_runtime.h>

#define NNODES 500000
#define KDIM 100
#define KP1 128
#define HDIM 256
#define MBLK 64
#define THREADS 256

typedef __attribute__((ext_vector_type(8))) short bf16x8;
typedef __attribute__((ext_vector_type(4))) float f32x4;

__device__ __forceinline__ unsigned rnd_bf(float f) {
    union { float f; unsigned u; } v; v.f = f;
    return v.u + 0x7fffu + ((v.u >> 16) & 1u);      // rne bias
}
// Single-instruction RNE pack of 2 f32 -> 2 bf16 (gfx950 v_cvt_pk_bf16_f32).
__device__ __forceinline__ unsigned pack2(float lo, float hi) {
    unsigned r;
    asm("v_cvt_pk_bf16_f32 %0, %1, %2" : "=v"(r) : "v"(lo), "v"(hi));
    return r;
}
// tanh(x) = 1 - 2/(1+e^{2x}); e^{2x} = 2^{x*2log2(e)}; rcp instead of IEEE div
// (default compile has no fast-math, so "/" emits div_scale/div_fmas/div_fixup).
__device__ __forceinline__ float fast_tanh(float x) {
    float e = __builtin_amdgcn_exp2f(x * 2.8853900817779268f);
    return 1.0f - 2.0f * __builtin_amdgcn_rcpf(e + 1.0f);
}
__device__ __forceinline__ float bflo(unsigned u) {
    union { unsigned u; float f; } v; v.u = u << 16; return v.f;
}
__device__ __forceinline__ float bfhi(unsigned u) {
    union { unsigned u; float f; } v; v.u = u & 0xffff0000u; return v.f;
}

// Pack weights into MFMA A-operand tiles (A = W^T): tile (kt, m16) at
// (kt*16+m16)*512; element lane*8+j = W[kt*32 + (lane>>4)*8 + j][m16*16 + (lane&15)].
__global__ void pack_all(const float* __restrict__ W1, const float* __restrict__ W2,
                         const float* __restrict__ W3,
                         unsigned short* __restrict__ w1p, unsigned short* __restrict__ w2p,
                         unsigned short* __restrict__ w3p) {
    int t = blockIdx.x * 256 + threadIdx.x;
    const float* src; unsigned short* dst; int ksrc;
    if (t < KP1 * HDIM)                    { src = W1; dst = w1p; ksrc = KDIM; }
    else if (t < KP1 * HDIM + HDIM * HDIM) { t -= KP1 * HDIM; src = W2; dst = w2p; ksrc = HDIM; }
    else                                   { t -= KP1 * HDIM + HDIM * HDIM; src = W3; dst = w3p; ksrc = HDIM; }
    int tile = t >> 9, r = t & 511, lane = r >> 3, j = r & 7;
    int kt = tile >> 4, m16 = tile & 15;
    int k = kt * 32 + ((lane >> 4) << 3) + j;
    int n = m16 * 16 + (lane & 15);
    float v = (k < ksrc) ? src[k * HDIM + n] : 0.0f;
    dst[tile * 512 + r] = (unsigned short)(rnd_bf(v) >> 16);
}

// Activations in LDS: [node][feature], element (n,f) at n*STRIDE + ((f>>3)^(n&7))*8 + (f&7).
// IN-PLACE layer: all K-loop reads of `buf` complete (barrier) before the
// epilogue overwrites `buf` with the next activations. One 32 KiB buffer
// serves 64 nodes x 256 feats for the whole layer chain.
// A = weight fragment (global, prepacked), B = activation fragment (LDS b128),
// D: row = feature (quad*4+reg -> consecutive), col = node.
template<int KSTEPS, int IN_STRIDE>
__device__ __forceinline__ void layer(unsigned short* buf,
                                      const unsigned short* __restrict__ wp,
                                      const float* __restrict__ bias, int tid) {
    const int lane = tid & 63;
    const int w = tid >> 6;            // wave owns features [w*64, w*64+64), all 64 nodes
    const int lrow = lane & 15;
    const int quad = lane >> 4;
    const int s = lrow & 7;            // swizzle key: node&7 == lrow&7 for all n-tiles

    f32x4 acc[4][4];
#pragma unroll
    for (int mt = 0; mt < 4; mt++) {
        f32x4 bv = *(const f32x4*)(bias + w * 64 + mt * 16 + quad * 4);
#pragma unroll
        for (int nt = 0; nt < 4; nt++) acc[mt][nt] = bv;
    }

    const unsigned short* wpw = wp + (w * 4) * 512 + lane * 8;

#pragma unroll 2
    for (int ks = 0; ks < KSTEPS; ks++) {
        const int gk = ks * 4 + quad;
        const int off = ((gk ^ s) << 3);
        bf16x8 b[4], a[4];
#pragma unroll
        for (int nt = 0; nt < 4; nt++)
            b[nt] = *(const bf16x8*)(buf + (nt * 16 + lrow) * IN_STRIDE + off);
#pragma unroll
        for (int mt = 0; mt < 4; mt++)
            a[mt] = *(const bf16x8*)(wpw + (ks * 16 + mt) * 512);
#pragma unroll
        for (int mt = 0; mt < 4; mt++)
#pragma unroll
            for (int nt = 0; nt < 4; nt++)
                acc[mt][nt] = __builtin_amdgcn_mfma_f32_16x16x32_bf16(a[mt], b[nt], acc[mt][nt], 0, 0, 0);
    }

    __syncthreads();                   // all waves done READING buf

#pragma unroll
    for (int mt = 0; mt < 4; mt++) {
        const int g = w * 8 + mt * 2 + (quad >> 1);      // feature granule
#pragma unroll
        for (int nt = 0; nt < 4; nt++) {
            const int node = nt * 16 + lrow;
            unsigned short* p = buf + node * HDIM + ((g ^ s) << 3) + ((quad & 1) << 2);
            f32x4 v = acc[mt][nt];
            uint2 pk;
            pk.x = pack2(fast_tanh(v[0]), fast_tanh(v[1]));
            pk.y = pack2(fast_tanh(v[2]), fast_tanh(v[3]));
            *(uint2*)p = pk;
        }
    }
    __syncthreads();                   // writes visible before next layer reads
}

// 4 waves/EU -> 128 VGPR/wave budget: acc[4][4] (64, unified AGPR half) +
// a/b frags (32) + addressing fits WITHOUT scratch spill. (256,5) spilled:
// WRITE_SIZE 1.9 MB -> 107 MB of scratch traffic, +13 us net.
__launch_bounds__(THREADS, 4)
__global__ void mlp_kernel(const float* __restrict__ ea,
                           const unsigned short* __restrict__ w1p,
                           const unsigned short* __restrict__ w2p,
                           const unsigned short* __restrict__ w3p,
                           const float* __restrict__ b1,
                           const float* __restrict__ b2,
                           const float* __restrict__ b3,
                           const float* __restrict__ w4,
                           const float* __restrict__ b4,
                           float* __restrict__ out) {
    __shared__ unsigned short X[MBLK * HDIM];       // 32 KiB, in-place all layers

    const int tid = threadIdx.x;
    const long rowbase = (long)blockIdx.x * MBLK;   // last block partial (32 rows)

    // stage e: 64 rows x 25 float4 -> bf16 (swizzled, stride KP1); zero OOB rows
    const float4* eav = (const float4*)(ea + rowbase * KDIM);
    for (int i = tid; i < MBLK * 25; i += THREADS) {
        int row = i / 25;
        int q = i - row * 25;
        float4 v = make_float4(0.f, 0.f, 0.f, 0.f);
        if (rowbase + row < NNODES) v = eav[i];
        unsigned short* p = X + row * KP1 + ((((q >> 1)) ^ (row & 7)) << 3) + ((q & 1) << 2);
        *(uint2*)p = make_uint2(pack2(v.x, v.y), pack2(v.z, v.w));
    }
    // zero-pad cols 100..127 (granule 12 upper half + granules 13..15)
    for (int i = tid; i < MBLK * 4; i += THREADS) {
        int row = i >> 2, c = i & 3;
        if (c == 0) {
            unsigned short* p = X + row * KP1 + ((12 ^ (row & 7)) << 3) + 4;
            *(uint2*)p = make_uint2(0u, 0u);
        } else {
            unsigned short* p = X + row * KP1 + (((12 + c) ^ (row & 7)) << 3);
            *(uint4*)p = make_uint4(0u, 0u, 0u, 0u);
        }
    }
    __syncthreads();

    layer<4, KP1>(X, w1p, b1, tid);     // L1: (64x128)@(128x256) tanh
    layer<8, HDIM>(X, w2p, b2, tid);    // L2
    layer<8, HDIM>(X, w3p, b3, tid);    // L3

    // head: out = sigmoid(h3 . W4 + b4); 4 lanes per node, 64 feats each
    {
        const int node = tid >> 2, part = tid & 3;
        const int s = node & 7;
        float sacc = 0.0f;
#pragma unroll
        for (int gg = 0; gg < 8; gg++) {
            const int g = part * 8 + gg;
            const uint4 hv = *(const uint4*)(X + node * HDIM + ((g ^ s) << 3));
            const float4 w0 = *(const float4*)(w4 + g * 8);
            const float4 w1 = *(const float4*)(w4 + g * 8 + 4);
            sacc += bflo(hv.x) * w0.x + bfhi(hv.x) * w0.y;
            sacc += bflo(hv.y) * w0.z + bfhi(hv.y) * w0.w;
            sacc += bflo(hv.z) * w1.x + bfhi(hv.z) * w1.y;
            sacc += bflo(hv.w) * w1.z + bfhi(hv.w) * w1.w;
        }
        sacc += __shfl_xor(sacc, 1);
        sacc += __shfl_xor(sacc, 2);
        if (part == 0 && rowbase + node < NNODES) {
            float z = sacc + b4[0];
            out[rowbase + node] =
                __builtin_amdgcn_rcpf(1.0f + __builtin_amdgcn_exp2f(-1.4426950408889634f * z));
        }
    }
}

extern "C" void kernel_launch(void* const* d_in, const int* in_sizes, int n_in,
                              void* d_out, int out_size, void* d_ws, size_t ws_size,
                              hipStream_t stream) {
    // inputs: 0:x 1:edge_index 2:edge_attr 3:W1 4:b1 5:W2 6:b2 7:W3 8:b3 9:W4 10:b4
    const float* ea = (const float*)d_in[2];
    const float* W1 = (const float*)d_in[3];
    const float* b1 = (const float*)d_in[4];
    const float* W2 = (const float*)d_in[5];
    const float* b2 = (const float*)d_in[6];
    const float* W3 = (const float*)d_in[7];
    const float* b3 = (const float*)d_in[8];
    const float* W4 = (const float*)d_in[9];
    const float* b4 = (const float*)d_in[10];
    float* out = (float*)d_out;

    unsigned short* w1p = (unsigned short*)d_ws;       // 128*256 bf16
    unsigned short* w2p = w1p + KP1 * HDIM;            // 256*256
    unsigned short* w3p = w2p + HDIM * HDIM;           // 256*256

    const int total = KP1 * HDIM + 2 * HDIM * HDIM;    // 163840
    pack_all<<<total / 256, 256, 0, stream>>>(W1, W2, W3, w1p, w2p, w3p);

    const int nblk = (NNODES + MBLK - 1) / MBLK;       // 7813, last block partial
    mlp_kernel<<<nblk, THREADS, 0, stream>>>(ea, w1p, w2p, w3p,
                                             b1, b2, b3, W4, b4, out);
}